// Round 13
// baseline (250.462 us; speedup 1.0000x reference)
//
#include <hip/hip_runtime.h>

#define NN 80000
#define NE 1280000
#define NG 2000
#define HID 64
#define FIN1 40
#define BSZ 128
#define NBUK (NN / BSZ)                  // 625 buckets
#define EB 8192
#define NBB ((NE + EB - 1) / EB)         // 157 blocks
#define NBBP 160
constexpr float EPS = 1e-5f;

typedef _Float16 f16;
typedef f16 f16x8 __attribute__((ext_vector_type(8)));
typedef float f32x4 __attribute__((ext_vector_type(4)));

// ---------------- setup: ids | wprep | graph bounds | f16 tables | zero -----
__global__ void setup(const int* __restrict__ sid, const int* __restrict__ cid,
                      const int* __restrict__ pid, const int* __restrict__ batch,
                      const float* __restrict__ stab, const float* __restrict__ ctab,
                      const float* __restrict__ ptab,
                      const float* __restrict__ W1l, const float* __restrict__ W1r,
                      const float* __restrict__ W2l, const float* __restrict__ W2r,
                      int* __restrict__ ids, f16* __restrict__ Bt1, f16* __restrict__ Bt2,
                      int* __restrict__ gstart,
                      f16* __restrict__ stab16, f16* __restrict__ ctab16,
                      f16* __restrict__ ptab16,
                      float* __restrict__ stats, int* __restrict__ bcnt) {
    int bid = blockIdx.x;
    int tid = threadIdx.x;
    if (bid < 313) {
        int n = bid * 256 + tid;
        if (n < NN) ids[n] = sid[n] | (cid[n] << 4) | (pid[n] << 8);
    } else if (bid < 373) {
        int i = (bid - 313) * 256 + tid;
        if (i < 64 * 104) {
            int j = i / 104, k = i - j * 104;
            float v = 0.f;
            if (k < 40) v = W1l[k * 64 + j];
            else if (k < 80) v = W1r[(k - 40) * 64 + j];
            Bt1[i] = (f16)v;
        }
        int i2 = i - 64 * 104;
        if (i2 >= 0 && i2 < 64 * 136) {
            int j = i2 / 136, k = i2 - j * 136;
            float v = 0.f;
            if (k < 64) v = W2l[k * 64 + j];
            else if (k < 128) v = W2r[(k - 64) * 64 + j];
            Bt2[i2] = (f16)v;
        }
    } else if (bid < 686) {
        int n = (bid - 373) * 256 + tid;
        if (n >= NN) return;
        int cur = batch[n];
        int prev = (n == 0) ? -1 : batch[n - 1];
        for (int g = prev + 1; g <= cur; g++) gstart[g] = n;
        if (n == NN - 1)
            for (int g = cur + 1; g <= NG; g++) gstart[g] = NN;
    } else if (bid < 720) {
        int i = (bid - 686) * 256 + tid;
        if (i < 256) stab16[i] = (f16)stab[i];
        else if (i < 512) ctab16[i - 256] = (f16)ctab[i - 256];
        else if (i < 512 + 8192) ptab16[i - 512] = (f16)ptab[i - 512];
    } else {                               // zero stats + bcnt
        if (tid < 256) stats[tid] = 0.f;
        for (int i = tid; i < NBUK; i += 256) bcnt[i] = 0;
    }
}

// ---------------- CSR build ----------------
__global__ void khist(const int* __restrict__ dst, int* __restrict__ bhistT,
                      int* __restrict__ bcnt) {
    __shared__ int lh[NBUK];
    for (int i = threadIdx.x; i < NBUK; i += 256) lh[i] = 0;
    __syncthreads();
    int e0 = blockIdx.x * EB, e1 = min(e0 + EB, NE);
    for (int e = e0 + threadIdx.x; e < e1; e += 256) atomicAdd(&lh[dst[e] >> 7], 1);
    __syncthreads();
    for (int i = threadIdx.x; i < NBUK; i += 256) {
        int c = lh[i];
        bhistT[i * NBBP + blockIdx.x] = c;
        if (c) atomicAdd(&bcnt[i], c);
    }
}

__global__ void kscan_a(const int* __restrict__ bcnt, int* __restrict__ bstart) {
    __shared__ int l[1024];
    int t = threadIdx.x;
    l[t] = (t < NBUK) ? bcnt[t] : 0;
    __syncthreads();
    for (int off = 1; off < 1024; off <<= 1) {
        int v = (t >= off) ? l[t - off] : 0;
        __syncthreads();
        l[t] += v;
        __syncthreads();
    }
    if (t < NBUK) bstart[t] = (t == 0) ? 0 : l[t - 1];
    if (t == NBUK) bstart[NBUK] = NE;
}

__global__ void kscan_b(const int* __restrict__ bhistT, const int* __restrict__ bstart,
                        int* __restrict__ lbaseT) {
    int b = blockIdx.x;
    int l = threadIdx.x;
    int run = bstart[b];
    for (int i0 = 0; i0 < NBB; i0 += 64) {
        int idx = i0 + l;
        int v = (idx < NBB) ? bhistT[b * NBBP + idx] : 0;
        int inc = v;
        for (int off = 1; off < 64; off <<= 1) {
            int tt = __shfl_up(inc, off);
            if (l >= off) inc += tt;
        }
        if (idx < NBB) lbaseT[b * NBBP + idx] = run + inc - v;
        run += __shfl(inc, 63);
    }
}

__global__ void kbin(const int* __restrict__ src, const int* __restrict__ dst,
                     const int* __restrict__ lbaseT, int* __restrict__ ebuf) {
    __shared__ int lcur[NBUK];
    for (int i = threadIdx.x; i < NBUK; i += 256) lcur[i] = lbaseT[i * NBBP + blockIdx.x];
    __syncthreads();
    int e0 = blockIdx.x * EB, e1 = min(e0 + EB, NE);
    for (int e = e0 + threadIdx.x; e < e1; e += 256) {
        int d = dst[e];
        int off = atomicAdd(&lcur[d >> 7], 1);
        ebuf[off] = (src[e] << 7) | (d & 127);
    }
}

__global__ void kfill(const int* __restrict__ ebuf, const int* __restrict__ bstart,
                      int* __restrict__ row_ptr, int* __restrict__ eidx) {
    __shared__ int cnt[BSZ];
    __shared__ int sb[BSZ];
    __shared__ int lcur[BSZ];
    int b = blockIdx.x, t = threadIdx.x;
    int nbase = b << 7;
    if (t < BSZ) cnt[t] = 0;
    __syncthreads();
    int s0 = bstart[b], s1 = bstart[b + 1];
    for (int i = s0 + t; i < s1; i += 256) atomicAdd(&cnt[ebuf[i] & 127], 1);
    __syncthreads();
    if (t < BSZ) sb[t] = cnt[t];
    __syncthreads();
    for (int off = 1; off < BSZ; off <<= 1) {
        int v = (t >= off && t < BSZ) ? sb[t - off] : 0;
        __syncthreads();
        if (t < BSZ) sb[t] += v;
        __syncthreads();
    }
    if (t < BSZ) {
        int excl = ((t == 0) ? 0 : sb[t - 1]) + s0;
        row_ptr[nbase + t] = excl;
        lcur[t] = excl;
    }
    if (b == 0 && t == 0) row_ptr[NN] = NE;
    __syncthreads();
    for (int i = s0 + t; i < s1; i += 256) {
        int v = ebuf[i];
        int pos = atomicAdd(&lcur[v & 127], 1);
        eidx[pos] = v >> 7;
    }
}

// ---------------- layer-1 gather: 12 groups x 5 lanes, direct eidx loads ----
__global__ void gather1(const int* __restrict__ row_ptr, const int* __restrict__ eidx,
                        const int* __restrict__ ids,
                        const f16* __restrict__ stab16, const f16* __restrict__ ctab16,
                        const f16* __restrict__ ptab16, f16* __restrict__ agg) {
    int tt = blockIdx.x * 256 + threadIdx.x;
    int n = tt >> 6;
    int lane = threadIdx.x & 63;
    if (n >= NN) return;
    int grp = lane / 5;            // 0..12 (lanes 60-63 idle in accum)
    int li = lane - grp * 5;       // 0..4
    bool lact = grp < 12;
    int beg = row_ptr[n], end = row_ptr[n + 1];
    float ac[8];
#pragma unroll
    for (int i = 0; i < 8; i++) ac[i] = 0.f;
    for (int j0 = beg; j0 < end; j0 += 60) {
        int cnt = min(60, end - j0);
        bool val[5];
        int sidx[5];
#pragma unroll
        for (int u = 0; u < 5; u++) {
            int e = u * 12 + grp;
            val[u] = lact && (e < cnt);
            sidx[u] = val[u] ? eidx[j0 + e] : 0;
        }
        int idv[5];
#pragma unroll
        for (int u = 0; u < 5; u++) idv[u] = val[u] ? ids[sidx[u]] : 0;
        f16x8 v[5];
#pragma unroll
        for (int u = 0; u < 5; u++) {
            if (val[u]) {
                int id = idv[u];
                const f16* rowp;
                if (li < 2)      rowp = &stab16[(id & 15) * 16 + li * 8];
                else if (li < 4) rowp = &ctab16[((id >> 4) & 15) * 16 + (li - 2) * 8];
                else             rowp = &ptab16[(id >> 8) * 8];
                v[u] = *(const f16x8*)rowp;
            }
        }
#pragma unroll
        for (int u = 0; u < 5; u++) {
            if (val[u]) {
#pragma unroll
                for (int i = 0; i < 8; i++) ac[i] += (float)v[u][i];
            }
        }
    }
    // reduce across the 12 groups: 12->6->3->(g0+=g2)->(g0+=g1)
#pragma unroll
    for (int i = 0; i < 8; i++) {
        float r;
        r = __shfl(ac[i], lane + 30); if (grp < 6) ac[i] += r;
        r = __shfl(ac[i], lane + 15); if (grp < 3) ac[i] += r;
        r = __shfl(ac[i], lane + 10); if (grp < 1) ac[i] += r;
        r = __shfl(ac[i], lane + 5);  if (grp < 1) ac[i] += r;
    }
    if (lane < 5) {
        float inv = 1.0f / (float)max(end - beg, 1);
        f16x8 o;
#pragma unroll
        for (int i = 0; i < 8; i++) o[i] = (f16)(ac[i] * inv);
        *(f16x8*)&agg[(size_t)n * FIN1 + lane * 8] = o;
    }
}

// ---------------- layer-2 gather: direct eidx loads, 8-deep pipeline --------
__global__ void gather2(const int* __restrict__ row_ptr, const int* __restrict__ eidx,
                        const f16* __restrict__ x, const float* __restrict__ stats,
                        const float* __restrict__ g1, const float* __restrict__ be1,
                        f16* __restrict__ agg) {
    int tt = blockIdx.x * 256 + threadIdx.x;
    int n = tt >> 6;
    int lane = threadIdx.x & 63;
    if (n >= NN) return;
    int grp = lane >> 3;
    int fl = (lane & 7) * 8;
    float sc8[8], sh8[8];
    {
        const float invn = 1.0f / (float)NN;
#pragma unroll
        for (int i = 0; i < 8; i++) {
            float m = stats[fl + i] * invn;
            float var = stats[64 + fl + i] * invn - m * m;
            float sc = g1[fl + i] * __frsqrt_rn(var + EPS);
            sc8[i] = sc;
            sh8[i] = be1[fl + i] - m * sc;
        }
    }
    int beg = row_ptr[n], end = row_ptr[n + 1];
    float ac[8];
#pragma unroll
    for (int i = 0; i < 8; i++) ac[i] = 0.f;
    for (int j0 = beg; j0 < end; j0 += 64) {
        int cnt = min(64, end - j0);
        bool val[8];
        f16x8 v[8];
#pragma unroll
        for (int u = 0; u < 8; u++) {
            int e = u * 8 + grp;
            val[u] = e < cnt;
            int s = val[u] ? eidx[j0 + e] : 0;
            if (val[u]) v[u] = *(const f16x8*)&x[(size_t)s * HID + fl];
        }
#pragma unroll
        for (int u = 0; u < 8; u++) {
            if (val[u]) {
#pragma unroll
                for (int i = 0; i < 8; i++)
                    ac[i] += fmaxf(fmaf((float)v[u][i], sc8[i], sh8[i]), 0.f);
            }
        }
    }
#pragma unroll
    for (int m = 8; m <= 32; m <<= 1) {
#pragma unroll
        for (int i = 0; i < 8; i++) ac[i] += __shfl_xor(ac[i], m);
    }
    if (lane < 8) {
        float inv = 1.0f / (float)max(end - beg, 1);
        f16x8 o;
#pragma unroll
        for (int i = 0; i < 8; i++) o[i] = (f16)(ac[i] * inv);
        *(f16x8*)&agg[(size_t)n * HID + fl] = o;
    }
}

// ---------------- MFMA layer 1: LDS-free fragments, fused BN stats ----------
__launch_bounds__(256)
__global__ void sage_mfma1(const int* __restrict__ ids, const f16* __restrict__ aggv,
                           const f16* __restrict__ stab16, const f16* __restrict__ ctab16,
                           const f16* __restrict__ ptab16,
                           const f16* __restrict__ Btg, const float* __restrict__ bias,
                           f16* __restrict__ h, float* __restrict__ stats) {
    __shared__ float sred[4][64];
    __shared__ float qred[4][64];
    const int KP = 104;

    int tid = threadIdx.x;
    int n0 = blockIdx.x * 64;
    int w = tid >> 6, l = tid & 63;
    int jloc = l & 15, kg = l >> 4;
    int n = n0 + w * 16 + jloc;

    f16x8 af[3];
#pragma unroll
    for (int kk = 0; kk < 3; kk++) {
        int c = kk * 4 + kg;
        if (c < 5) {
            af[kk] = *(const f16x8*)&aggv[(size_t)n * FIN1 + c * 8];
        } else if (c < 10) {
            int id = ids[n];
            int cc = c - 5;
            const f16* rowp;
            if (cc < 2)      rowp = &stab16[(id & 15) * 16 + cc * 8];
            else if (cc < 4) rowp = &ctab16[((id >> 4) & 15) * 16 + (cc - 2) * 8];
            else             rowp = &ptab16[(id >> 8) * 8];
            af[kk] = *(const f16x8*)rowp;
        } else {
#pragma unroll
            for (int i = 0; i < 8; i++) af[kk][i] = (f16)0.f;
        }
    }

    f32x4 acc[4];
#pragma unroll
    for (int jt = 0; jt < 4; jt++) {
        float bj = bias[jt * 16 + jloc];
        acc[jt] = (f32x4){bj, bj, bj, bj};
    }
#pragma unroll
    for (int kk = 0; kk < 3; kk++) {
#pragma unroll
        for (int jt = 0; jt < 4; jt++) {
            f16x8 bf = *(const f16x8*)&Btg[(jt * 16 + jloc) * KP + kk * 32 + kg * 8];
            acc[jt] = __builtin_amdgcn_mfma_f32_16x16x32_f16(af[kk], bf, acc[jt], 0, 0, 0);
        }
    }
#pragma unroll
    for (int jt = 0; jt < 4; jt++) {
        float sv = 0.f, qv = 0.f;
#pragma unroll
        for (int reg = 0; reg < 4; reg++) {
            f16 hv = (f16)acc[jt][reg];
            int nn2 = n0 + w * 16 + kg * 4 + reg;
            h[(size_t)nn2 * HID + jt * 16 + jloc] = hv;
            float v = (float)hv;
            sv += v; qv += v * v;
        }
        sv += __shfl_xor(sv, 16); sv += __shfl_xor(sv, 32);
        qv += __shfl_xor(qv, 16); qv += __shfl_xor(qv, 32);
        if (kg == 0) { sred[w][jt * 16 + jloc] = sv; qred[w][jt * 16 + jloc] = qv; }
    }
    __syncthreads();
    if (tid < 128) {
        int f2 = tid & 63, which = tid >> 6;
        float r = which ? (qred[0][f2] + qred[1][f2] + qred[2][f2] + qred[3][f2])
                        : (sred[0][f2] + sred[1][f2] + sred[2][f2] + sred[3][f2]);
        atomicAdd(&stats[which * 64 + f2], r);
    }
}

// ---------------- MFMA layer 2: LDS-free fragments, BN1 on xr, BN2 stats ----
__launch_bounds__(256)
__global__ void sage_mfma2(const f16* __restrict__ x, const f16* __restrict__ aggv,
                           const f16* __restrict__ Btg, const float* __restrict__ bias,
                           f16* __restrict__ h,
                           const float* __restrict__ stats1, const float* __restrict__ g1,
                           const float* __restrict__ be1, float* __restrict__ stats) {
    __shared__ float ssc[64], ssh[64];
    __shared__ float sred[4][64];
    __shared__ float qred[4][64];
    const int KP = 136;

    int tid = threadIdx.x;
    int n0 = blockIdx.x * 64;
    if (tid < 64) {
        const float invn = 1.0f / (float)NN;
        float m = stats1[tid] * invn;
        float var = stats1[64 + tid] * invn - m * m;
        float sc = g1[tid] * __frsqrt_rn(var + EPS);
        ssc[tid] = sc;
        ssh[tid] = be1[tid] - m * sc;
    }
    __syncthreads();

    int w = tid >> 6, l = tid & 63;
    int jloc = l & 15, kg = l >> 4;
    int n = n0 + w * 16 + jloc;

    f16x8 af[4];
#pragma unroll
    for (int kk = 0; kk < 4; kk++) {
        int c = kk * 4 + kg;
        if (c < 8) {
            af[kk] = *(const f16x8*)&aggv[(size_t)n * HID + c * 8];
        } else {
            int fb = (c - 8) * 8;
            f16x8 vx = *(const f16x8*)&x[(size_t)n * HID + fb];
#pragma unroll
            for (int i = 0; i < 8; i++)
                af[kk][i] = (f16)fmaxf(fmaf((float)vx[i], ssc[fb + i], ssh[fb + i]), 0.f);
        }
    }

    f32x4 acc[4];
#pragma unroll
    for (int jt = 0; jt < 4; jt++) {
        float bj = bias[jt * 16 + jloc];
        acc[jt] = (f32x4){bj, bj, bj, bj};
    }
#pragma unroll
    for (int kk = 0; kk < 4; kk++) {
#pragma unroll
        for (int jt = 0; jt < 4; jt++) {
            f16x8 bf = *(const f16x8*)&Btg[(jt * 16 + jloc) * KP + kk * 32 + kg * 8];
            acc[jt] = __builtin_amdgcn_mfma_f32_16x16x32_f16(af[kk], bf, acc[jt], 0, 0, 0);
        }
    }
#pragma unroll
    for (int jt = 0; jt < 4; jt++) {
        float sv = 0.f, qv = 0.f;
#pragma unroll
        for (int reg = 0; reg < 4; reg++) {
            f16 hv = (f16)acc[jt][reg];
            int nn2 = n0 + w * 16 + kg * 4 + reg;
            h[(size_t)nn2 * HID + jt * 16 + jloc] = hv;
            float v = (float)hv;
            sv += v; qv += v * v;
        }
        sv += __shfl_xor(sv, 16); sv += __shfl_xor(sv, 32);
        qv += __shfl_xor(qv, 16); qv += __shfl_xor(qv, 32);
        if (kg == 0) { sred[w][jt * 16 + jloc] = sv; qred[w][jt * 16 + jloc] = qv; }
    }
    __syncthreads();
    if (tid < 128) {
        int f2 = tid & 63, which = tid >> 6;
        float r = which ? (qred[0][f2] + qred[1][f2] + qred[2][f2] + qred[3][f2])
                        : (sred[0][f2] + sred[1][f2] + sred[2][f2] + sred[3][f2]);
        atomicAdd(&stats[which * 64 + f2], r);
    }
}

// ---------------- fused BN2+ReLU + mean-pool + output GEMV ----------------
__global__ void pool_out(const f16* __restrict__ h, const float* __restrict__ stats2,
                         const float* __restrict__ g2, const float* __restrict__ be2,
                         const int* __restrict__ gstart,
                         const float* __restrict__ Wout, const float* __restrict__ bout,
                         float* __restrict__ out) {
    int w = (blockIdx.x * blockDim.x + threadIdx.x) >> 6;
    int f = threadIdx.x & 63;
    if (w >= NG) return;
    const float invn = 1.0f / (float)NN;
    float m = stats2[f] * invn;
    float var = stats2[64 + f] * invn - m * m;
    float sc = g2[f] / sqrtf(var + EPS);
    float sh = be2[f] - m * sc;
    int n0 = gstart[w], n1 = gstart[w + 1];
    float acc = 0.f;
    for (int n = n0; n < n1; n++) {
        float v = fmaf((float)h[(size_t)n * HID + f], sc, sh);
        acc += fmaxf(v, 0.0f);
    }
    float inv = 1.0f / (float)max(n1 - n0, 1);
    float p = acc * inv;
    float a0 = p * Wout[f * 2 + 0];
    float a1 = p * Wout[f * 2 + 1];
#pragma unroll
    for (int mm = 1; mm < 64; mm <<= 1) {
        a0 += __shfl_xor(a0, mm);
        a1 += __shfl_xor(a1, mm);
    }
    if (f == 0) {
        out[w * 2 + 0] = a0 + bout[0];
        out[w * 2 + 1] = a1 + bout[1];
    }
}

extern "C" void kernel_launch(void* const* d_in, const int* in_sizes, int n_in,
                              void* d_out, int out_size, void* d_ws, size_t ws_size,
                              hipStream_t stream) {
    const int* sid = (const int*)d_in[0];
    const int* cid = (const int*)d_in[1];
    const int* pid = (const int*)d_in[2];
    const int* ei = (const int*)d_in[3];
    const int* batch = (const int*)d_in[4];
    const float* stab = (const float*)d_in[6];
    const float* ctab = (const float*)d_in[7];
    const float* ptab = (const float*)d_in[8];
    const float* W1l = (const float*)d_in[9];
    const float* b1 = (const float*)d_in[10];
    const float* W1r = (const float*)d_in[11];
    const float* g1 = (const float*)d_in[12];
    const float* be1 = (const float*)d_in[13];
    const float* W2l = (const float*)d_in[14];
    const float* b2 = (const float*)d_in[15];
    const float* W2r = (const float*)d_in[16];
    const float* g2 = (const float*)d_in[17];
    const float* be2 = (const float*)d_in[18];
    const float* Wout = (const float*)d_in[19];
    const float* bout = (const float*)d_in[20];

    const int* src = ei;
    const int* dst = ei + NE;

    char* p = (char*)d_ws;
    f16* agg = (f16*)p;        p += (size_t)NN * HID * 2;
    f16* h1 = (f16*)p;         p += (size_t)NN * HID * 2;
    f16* h2 = (f16*)p;         p += (size_t)NN * HID * 2;
    f16* bt1 = (f16*)p;        p += 64 * 104 * 2;
    f16* bt2 = (f16*)p;        p += 64 * 136 * 2;
    f16* stab16 = (f16*)p;     p += 256 * 2;
    f16* ctab16 = (f16*)p;     p += 256 * 2;
    f16* ptab16 = (f16*)p;     p += 8192 * 2;
    float* stats = (float*)p;  p += 256 * 4;
    int* bcnt = (int*)p;       p += NBUK * 4;
    int* ids = (int*)p;        p += (size_t)NN * 4;
    int* row_ptr = (int*)p;    p += (NN + 1) * 4;
    int* gstart = (int*)p;     p += (NG + 1) * 4;
    int* bstart = (int*)p;     p += (NBUK + 1) * 4;
    int* bhistT = (int*)p;     p += (size_t)NBUK * NBBP * 4;
    int* lbaseT = (int*)p;     p += (size_t)NBUK * NBBP * 4;
    int* ebuf = (int*)p;       p += (size_t)NE * 4;
    int* eidx = (int*)p;       p += (size_t)NE * 4;

    const int B = 256;

    setup<<<721, B, 0, stream>>>(sid, cid, pid, batch, stab, ctab, ptab,
                                 W1l, W1r, W2l, W2r,
                                 ids, bt1, bt2, gstart, stab16, ctab16, ptab16,
                                 stats, bcnt);

    khist<<<NBB, B, 0, stream>>>(dst, bhistT, bcnt);
    kscan_a<<<1, 1024, 0, stream>>>(bcnt, bstart);
    kscan_b<<<NBUK, 64, 0, stream>>>(bhistT, bstart, lbaseT);
    kbin<<<NBB, B, 0, stream>>>(src, dst, lbaseT, ebuf);
    kfill<<<NBUK, B, 0, stream>>>(ebuf, bstart, row_ptr, eidx);

    // ---- layer 1 ----
    gather1<<<(NN * 64 + B - 1) / B, B, 0, stream>>>(row_ptr, eidx, ids,
                                                     stab16, ctab16, ptab16, agg);
    sage_mfma1<<<NN / 64, B, 0, stream>>>(ids, agg, stab16, ctab16, ptab16,
                                          bt1, b1, h1, stats);

    // ---- layer 2 ----
    gather2<<<(NN * 64 + B - 1) / B, B, 0, stream>>>(row_ptr, eidx, h1, stats, g1, be1, agg);
    sage_mfma2<<<NN / 64, B, 0, stream>>>(h1, agg, bt2, b2, h2,
                                          stats, g1, be1, stats + 128);

    // ---- fused BN2+ReLU+pool+head ----
    pool_out<<<(NG * 64 + B - 1) / B, B, 0, stream>>>(h2, stats + 128, g2, be2, gstart,
                                                      Wout, bout, (float*)d_out);
}

// Round 14
// 228.126 us; speedup vs baseline: 1.0979x; 1.0979x over previous
//
#include <hip/hip_runtime.h>

#define NN 80000
#define NE 1280000
#define NG 2000
#define HID 64
#define FIN1 40
#define BSZ 128
#define NBUK (NN / BSZ)                  // 625 buckets
#define EB 8192
#define NBB ((NE + EB - 1) / EB)         // 157 blocks
#define NBBP 160
constexpr float EPS = 1e-5f;

typedef _Float16 f16;
typedef f16 f16x8 __attribute__((ext_vector_type(8)));
typedef float f32x4 __attribute__((ext_vector_type(4)));

// ---------------- setup: ids | wprep | graph bounds | f16 tables | zero -----
__global__ void setup(const int* __restrict__ sid, const int* __restrict__ cid,
                      const int* __restrict__ pid, const int* __restrict__ batch,
                      const float* __restrict__ stab, const float* __restrict__ ctab,
                      const float* __restrict__ ptab,
                      const float* __restrict__ W1l, const float* __restrict__ W1r,
                      const float* __restrict__ W2l, const float* __restrict__ W2r,
                      int* __restrict__ ids, f16* __restrict__ Bt1, f16* __restrict__ Bt2,
                      int* __restrict__ gstart,
                      f16* __restrict__ stab16, f16* __restrict__ ctab16,
                      f16* __restrict__ ptab16,
                      float* __restrict__ stats, int* __restrict__ bcnt) {
    int bid = blockIdx.x;
    int tid = threadIdx.x;
    if (bid < 313) {
        int n = bid * 256 + tid;
        if (n < NN) ids[n] = sid[n] | (cid[n] << 4) | (pid[n] << 8);
    } else if (bid < 373) {
        int i = (bid - 313) * 256 + tid;
        if (i < 64 * 104) {
            int j = i / 104, k = i - j * 104;
            float v = 0.f;
            if (k < 40) v = W1l[k * 64 + j];
            else if (k < 80) v = W1r[(k - 40) * 64 + j];
            Bt1[i] = (f16)v;
        }
        int i2 = i - 64 * 104;
        if (i2 >= 0 && i2 < 64 * 136) {
            int j = i2 / 136, k = i2 - j * 136;
            float v = 0.f;
            if (k < 64) v = W2l[k * 64 + j];
            else if (k < 128) v = W2r[(k - 64) * 64 + j];
            Bt2[i2] = (f16)v;
        }
    } else if (bid < 686) {
        int n = (bid - 373) * 256 + tid;
        if (n >= NN) return;
        int cur = batch[n];
        int prev = (n == 0) ? -1 : batch[n - 1];
        for (int g = prev + 1; g <= cur; g++) gstart[g] = n;
        if (n == NN - 1)
            for (int g = cur + 1; g <= NG; g++) gstart[g] = NN;
    } else if (bid < 720) {
        int i = (bid - 686) * 256 + tid;
        if (i < 256) stab16[i] = (f16)stab[i];
        else if (i < 512) ctab16[i - 256] = (f16)ctab[i - 256];
        else if (i < 512 + 8192) ptab16[i - 512] = (f16)ptab[i - 512];
    } else {
        if (tid < 256) stats[tid] = 0.f;
        for (int i = tid; i < NBUK; i += 256) bcnt[i] = 0;
    }
}

// ---------------- CSR build ----------------
__global__ void khist(const int* __restrict__ dst, int* __restrict__ bhistT,
                      int* __restrict__ bcnt) {
    __shared__ int lh[NBUK];
    for (int i = threadIdx.x; i < NBUK; i += 256) lh[i] = 0;
    __syncthreads();
    int e0 = blockIdx.x * EB, e1 = min(e0 + EB, NE);
    for (int e = e0 + threadIdx.x; e < e1; e += 256) atomicAdd(&lh[dst[e] >> 7], 1);
    __syncthreads();
    for (int i = threadIdx.x; i < NBUK; i += 256) {
        int c = lh[i];
        bhistT[i * NBBP + blockIdx.x] = c;
        if (c) atomicAdd(&bcnt[i], c);
    }
}

__global__ void kscan_a(const int* __restrict__ bcnt, int* __restrict__ bstart) {
    __shared__ int l[1024];
    int t = threadIdx.x;
    l[t] = (t < NBUK) ? bcnt[t] : 0;
    __syncthreads();
    for (int off = 1; off < 1024; off <<= 1) {
        int v = (t >= off) ? l[t - off] : 0;
        __syncthreads();
        l[t] += v;
        __syncthreads();
    }
    if (t < NBUK) bstart[t] = (t == 0) ? 0 : l[t - 1];
    if (t == NBUK) bstart[NBUK] = NE;
}

__global__ void kscan_b(const int* __restrict__ bhistT, const int* __restrict__ bstart,
                        int* __restrict__ lbaseT) {
    int b = blockIdx.x;
    int l = threadIdx.x;
    int run = bstart[b];
    for (int i0 = 0; i0 < NBB; i0 += 64) {
        int idx = i0 + l;
        int v = (idx < NBB) ? bhistT[b * NBBP + idx] : 0;
        int inc = v;
        for (int off = 1; off < 64; off <<= 1) {
            int tt = __shfl_up(inc, off);
            if (l >= off) inc += tt;
        }
        if (idx < NBB) lbaseT[b * NBBP + idx] = run + inc - v;
        run += __shfl(inc, 63);
    }
}

__global__ void kbin(const int* __restrict__ src, const int* __restrict__ dst,
                     const int* __restrict__ lbaseT, int* __restrict__ ebuf) {
    __shared__ int lcur[NBUK];
    for (int i = threadIdx.x; i < NBUK; i += 256) lcur[i] = lbaseT[i * NBBP + blockIdx.x];
    __syncthreads();
    int e0 = blockIdx.x * EB, e1 = min(e0 + EB, NE);
    for (int e = e0 + threadIdx.x; e < e1; e += 256) {
        int d = dst[e];
        int off = atomicAdd(&lcur[d >> 7], 1);
        ebuf[off] = (src[e] << 7) | (d & 127);
    }
}

__global__ void kfill(const int* __restrict__ ebuf, const int* __restrict__ bstart,
                      int* __restrict__ row_ptr, int* __restrict__ eidx) {
    __shared__ int cnt[BSZ];
    __shared__ int sb[BSZ];
    __shared__ int lcur[BSZ];
    int b = blockIdx.x, t = threadIdx.x;
    int nbase = b << 7;
    if (t < BSZ) cnt[t] = 0;
    __syncthreads();
    int s0 = bstart[b], s1 = bstart[b + 1];
    for (int i = s0 + t; i < s1; i += 256) atomicAdd(&cnt[ebuf[i] & 127], 1);
    __syncthreads();
    if (t < BSZ) sb[t] = cnt[t];
    __syncthreads();
    for (int off = 1; off < BSZ; off <<= 1) {
        int v = (t >= off && t < BSZ) ? sb[t - off] : 0;
        __syncthreads();
        if (t < BSZ) sb[t] += v;
        __syncthreads();
    }
    if (t < BSZ) {
        int excl = ((t == 0) ? 0 : sb[t - 1]) + s0;
        row_ptr[nbase + t] = excl;
        lcur[t] = excl;
    }
    if (b == 0 && t == 0) row_ptr[NN] = NE;
    __syncthreads();
    for (int i = s0 + t; i < s1; i += 256) {
        int v = ebuf[i];
        int pos = atomicAdd(&lcur[v & 127], 1);
        eidx[pos] = v >> 7;
    }
}

// ---------------- layer-1 gather: packed-f16 accumulate ----------------
__global__ void gather1(const int* __restrict__ row_ptr, const int* __restrict__ eidx,
                        const int* __restrict__ ids,
                        const f16* __restrict__ stab16, const f16* __restrict__ ctab16,
                        const f16* __restrict__ ptab16, f16* __restrict__ agg) {
    int tt = blockIdx.x * 256 + threadIdx.x;
    int n = tt >> 6;
    int lane = threadIdx.x & 63;
    if (n >= NN) return;
    int grp = lane >> 3, li = lane & 7;
    bool act = li < 5;
    int beg = row_ptr[n], end = row_ptr[n + 1];
    f16x8 ach;
#pragma unroll
    for (int i = 0; i < 8; i++) ach[i] = (f16)0.f;
    for (int j0 = beg; j0 < end; j0 += 64) {
        int cnt = min(64, end - j0);
        int myid = (j0 + lane < end) ? eidx[j0 + lane] : 0;
        int steps = (cnt + 7) >> 3;
        for (int u = 0; u < steps; u++) {
            int e = u * 8 + grp;
            int s = __shfl(myid, e);
            if (e < cnt && act) {
                int id = ids[s];
                const f16* rowp;
                if (li < 2)      rowp = &stab16[(id & 15) * 16 + li * 8];
                else if (li < 4) rowp = &ctab16[((id >> 4) & 15) * 16 + (li - 2) * 8];
                else             rowp = &ptab16[(id >> 8) * 8];
                ach += *(const f16x8*)rowp;     // v_pk_add_f16 x4
            }
        }
    }
    float ac[8];
#pragma unroll
    for (int i = 0; i < 8; i++) ac[i] = (float)ach[i];
#pragma unroll
    for (int m = 8; m <= 32; m <<= 1) {
#pragma unroll
        for (int i = 0; i < 8; i++) ac[i] += __shfl_xor(ac[i], m);
    }
    if (lane < 5) {
        float inv = 1.0f / (float)max(end - beg, 1);
        f16x8 o;
#pragma unroll
        for (int i = 0; i < 8; i++) o[i] = (f16)(ac[i] * inv);
        *(f16x8*)&agg[(size_t)n * FIN1 + lane * 8] = o;
    }
}

// ---------------- BN apply + ReLU, in-place f16 (h1 -> x1) ----------------
__global__ void bn_apply16(f16* __restrict__ h, const float* __restrict__ stats,
                           const float* __restrict__ g, const float* __restrict__ be) {
    __shared__ float ssc[64], ssh[64];
    int tid = threadIdx.x;
    if (tid < 64) {
        const float invn = 1.0f / (float)NN;
        float m = stats[tid] * invn;
        float var = stats[64 + tid] * invn - m * m;
        float sc = g[tid] * __frsqrt_rn(var + EPS);
        ssc[tid] = sc;
        ssh[tid] = be[tid] - m * sc;
    }
    __syncthreads();
    int idx = blockIdx.x * 256 + tid;      // unit of 8 f16
    if (idx >= NN * 8) return;
    int f = (idx & 7) * 8;
    f16x8 v = *(f16x8*)&h[(size_t)idx * 8];
    f16x8 o;
#pragma unroll
    for (int i = 0; i < 8; i++) {
        float xv = (float)v[i];
        o[i] = (f16)fmaxf(fmaf(xv, ssc[f + i], ssh[f + i]), 0.f);
    }
    *(f16x8*)&h[(size_t)idx * 8] = o;
}

// ---------------- layer-2 gather: raw sum, packed-f16 accumulate ------------
__global__ void gather2(const int* __restrict__ row_ptr, const int* __restrict__ eidx,
                        const f16* __restrict__ x, f16* __restrict__ agg) {
    int tt = blockIdx.x * 256 + threadIdx.x;
    int n = tt >> 6;
    int lane = threadIdx.x & 63;
    if (n >= NN) return;
    int grp = lane >> 3;
    int fl = (lane & 7) * 8;
    int beg = row_ptr[n], end = row_ptr[n + 1];
    f16x8 ach;
#pragma unroll
    for (int i = 0; i < 8; i++) ach[i] = (f16)0.f;
    for (int j0 = beg; j0 < end; j0 += 64) {
        int cnt = min(64, end - j0);
        int myid = (j0 + lane < end) ? eidx[j0 + lane] : 0;
        int steps = (cnt + 7) >> 3;
        for (int u = 0; u < steps; u++) {
            int e = u * 8 + grp;
            int s = __shfl(myid, e);
            if (e < cnt) {
                ach += *(const f16x8*)&x[(size_t)s * HID + fl];   // v_pk_add_f16 x4
            }
        }
    }
    float ac[8];
#pragma unroll
    for (int i = 0; i < 8; i++) ac[i] = (float)ach[i];
#pragma unroll
    for (int m = 8; m <= 32; m <<= 1) {
#pragma unroll
        for (int i = 0; i < 8; i++) ac[i] += __shfl_xor(ac[i], m);
    }
    if (lane < 8) {
        float inv = 1.0f / (float)max(end - beg, 1);
        f16x8 o;
#pragma unroll
        for (int i = 0; i < 8; i++) o[i] = (f16)(ac[i] * inv);
        *(f16x8*)&agg[(size_t)n * HID + fl] = o;
    }
}

// ---------------- MFMA layer 1: LDS-free fragments, fused BN stats ----------
__launch_bounds__(256)
__global__ void sage_mfma1(const int* __restrict__ ids, const f16* __restrict__ aggv,
                           const f16* __restrict__ stab16, const f16* __restrict__ ctab16,
                           const f16* __restrict__ ptab16,
                           const f16* __restrict__ Btg, const float* __restrict__ bias,
                           f16* __restrict__ h, float* __restrict__ stats) {
    __shared__ float sred[4][64];
    __shared__ float qred[4][64];
    const int KP = 104;

    int tid = threadIdx.x;
    int n0 = blockIdx.x * 64;
    int w = tid >> 6, l = tid & 63;
    int jloc = l & 15, kg = l >> 4;
    int n = n0 + w * 16 + jloc;

    f16x8 af[3];
#pragma unroll
    for (int kk = 0; kk < 3; kk++) {
        int c = kk * 4 + kg;
        if (c < 5) {
            af[kk] = *(const f16x8*)&aggv[(size_t)n * FIN1 + c * 8];
        } else if (c < 10) {
            int id = ids[n];
            int cc = c - 5;
            const f16* rowp;
            if (cc < 2)      rowp = &stab16[(id & 15) * 16 + cc * 8];
            else if (cc < 4) rowp = &ctab16[((id >> 4) & 15) * 16 + (cc - 2) * 8];
            else             rowp = &ptab16[(id >> 8) * 8];
            af[kk] = *(const f16x8*)rowp;
        } else {
#pragma unroll
            for (int i = 0; i < 8; i++) af[kk][i] = (f16)0.f;
        }
    }

    f32x4 acc[4];
#pragma unroll
    for (int jt = 0; jt < 4; jt++) {
        float bj = bias[jt * 16 + jloc];
        acc[jt] = (f32x4){bj, bj, bj, bj};
    }
#pragma unroll
    for (int kk = 0; kk < 3; kk++) {
#pragma unroll
        for (int jt = 0; jt < 4; jt++) {
            f16x8 bf = *(const f16x8*)&Btg[(jt * 16 + jloc) * KP + kk * 32 + kg * 8];
            acc[jt] = __builtin_amdgcn_mfma_f32_16x16x32_f16(af[kk], bf, acc[jt], 0, 0, 0);
        }
    }
#pragma unroll
    for (int jt = 0; jt < 4; jt++) {
        float sv = 0.f, qv = 0.f;
#pragma unroll
        for (int reg = 0; reg < 4; reg++) {
            f16 hv = (f16)acc[jt][reg];
            int nn2 = n0 + w * 16 + kg * 4 + reg;
            h[(size_t)nn2 * HID + jt * 16 + jloc] = hv;
            float v = (float)hv;
            sv += v; qv += v * v;
        }
        sv += __shfl_xor(sv, 16); sv += __shfl_xor(sv, 32);
        qv += __shfl_xor(qv, 16); qv += __shfl_xor(qv, 32);
        if (kg == 0) { sred[w][jt * 16 + jloc] = sv; qred[w][jt * 16 + jloc] = qv; }
    }
    __syncthreads();
    if (tid < 128) {
        int f2 = tid & 63, which = tid >> 6;
        float r = which ? (qred[0][f2] + qred[1][f2] + qred[2][f2] + qred[3][f2])
                        : (sred[0][f2] + sred[1][f2] + sred[2][f2] + sred[3][f2]);
        atomicAdd(&stats[which * 64 + f2], r);
    }
}

// ---------------- MFMA layer 2: LDS-free fragments, fused BN2 stats ---------
__launch_bounds__(256)
__global__ void sage_mfma2(const f16* __restrict__ x, const f16* __restrict__ aggv,
                           const f16* __restrict__ Btg, const float* __restrict__ bias,
                           f16* __restrict__ h, float* __restrict__ stats) {
    __shared__ float sred[4][64];
    __shared__ float qred[4][64];
    const int KP = 136;

    int tid = threadIdx.x;
    int n0 = blockIdx.x * 64;
    int w = tid >> 6, l = tid & 63;
    int jloc = l & 15, kg = l >> 4;
    int n = n0 + w * 16 + jloc;

    f16x8 af[4];
#pragma unroll
    for (int kk = 0; kk < 4; kk++) {
        int c = kk * 4 + kg;
        if (c < 8) af[kk] = *(const f16x8*)&aggv[(size_t)n * HID + c * 8];
        else       af[kk] = *(const f16x8*)&x[(size_t)n * HID + (c - 8) * 8];
    }

    f32x4 acc[4];
#pragma unroll
    for (int jt = 0; jt < 4; jt++) {
        float bj = bias[jt * 16 + jloc];
        acc[jt] = (f32x4){bj, bj, bj, bj};
    }
#pragma unroll
    for (int kk = 0; kk < 4; kk++) {
#pragma unroll
        for (int jt = 0; jt < 4; jt++) {
            f16x8 bf = *(const f16x8*)&Btg[(jt * 16 + jloc) * KP + kk * 32 + kg * 8];
            acc[jt] = __builtin_amdgcn_mfma_f32_16x16x32_f16(af[kk], bf, acc[jt], 0, 0, 0);
        }
    }
#pragma unroll
    for (int jt = 0; jt < 4; jt++) {
        float sv = 0.f, qv = 0.f;
#pragma unroll
        for (int reg = 0; reg < 4; reg++) {
            f16 hv = (f16)acc[jt][reg];
            int nn2 = n0 + w * 16 + kg * 4 + reg;
            h[(size_t)nn2 * HID + jt * 16 + jloc] = hv;
            float v = (float)hv;
            sv += v; qv += v * v;
        }
        sv += __shfl_xor(sv, 16); sv += __shfl_xor(sv, 32);
        qv += __shfl_xor(qv, 16); qv += __shfl_xor(qv, 32);
        if (kg == 0) { sred[w][jt * 16 + jloc] = sv; qred[w][jt * 16 + jloc] = qv; }
    }
    __syncthreads();
    if (tid < 128) {
        int f2 = tid & 63, which = tid >> 6;
        float r = which ? (qred[0][f2] + qred[1][f2] + qred[2][f2] + qred[3][f2])
                        : (sred[0][f2] + sred[1][f2] + sred[2][f2] + sred[3][f2]);
        atomicAdd(&stats[which * 64 + f2], r);
    }
}

// ---------------- fused BN2+ReLU + mean-pool + output GEMV ----------------
__global__ void pool_out(const f16* __restrict__ h, const float* __restrict__ stats2,
                         const float* __restrict__ g2, const float* __restrict__ be2,
                         const int* __restrict__ gstart,
                         const float* __restrict__ Wout, const float* __restrict__ bout,
                         float* __restrict__ out) {
    int w = (blockIdx.x * blockDim.x + threadIdx.x) >> 6;
    int f = threadIdx.x & 63;
    if (w >= NG) return;
    const float invn = 1.0f / (float)NN;
    float m = stats2[f] * invn;
    float var = stats2[64 + f] * invn - m * m;
    float sc = g2[f] / sqrtf(var + EPS);
    float sh = be2[f] - m * sc;
    int n0 = gstart[w], n1 = gstart[w + 1];
    float acc = 0.f;
    for (int n = n0; n < n1; n++) {
        float v = fmaf((float)h[(size_t)n * HID + f], sc, sh);
        acc += fmaxf(v, 0.0f);
    }
    float inv = 1.0f / (float)max(n1 - n0, 1);
    float p = acc * inv;
    float a0 = p * Wout[f * 2 + 0];
    float a1 = p * Wout[f * 2 + 1];
#pragma unroll
    for (int mm = 1; mm < 64; mm <<= 1) {
        a0 += __shfl_xor(a0, mm);
        a1 += __shfl_xor(a1, mm);
    }
    if (f == 0) {
        out[w * 2 + 0] = a0 + bout[0];
        out[w * 2 + 1] = a1 + bout[1];
    }
}

extern "C" void kernel_launch(void* const* d_in, const int* in_sizes, int n_in,
                              void* d_out, int out_size, void* d_ws, size_t ws_size,
                              hipStream_t stream) {
    const int* sid = (const int*)d_in[0];
    const int* cid = (const int*)d_in[1];
    const int* pid = (const int*)d_in[2];
    const int* ei = (const int*)d_in[3];
    const int* batch = (const int*)d_in[4];
    const float* stab = (const float*)d_in[6];
    const float* ctab = (const float*)d_in[7];
    const float* ptab = (const float*)d_in[8];
    const float* W1l = (const float*)d_in[9];
    const float* b1 = (const float*)d_in[10];
    const float* W1r = (const float*)d_in[11];
    const float* g1 = (const float*)d_in[12];
    const float* be1 = (const float*)d_in[13];
    const float* W2l = (const float*)d_in[14];
    const float* b2 = (const float*)d_in[15];
    const float* W2r = (const float*)d_in[16];
    const float* g2 = (const float*)d_in[17];
    const float* be2 = (const float*)d_in[18];
    const float* Wout = (const float*)d_in[19];
    const float* bout = (const float*)d_in[20];

    const int* src = ei;
    const int* dst = ei + NE;

    char* p = (char*)d_ws;
    f16* agg = (f16*)p;        p += (size_t)NN * HID * 2;
    f16* h1 = (f16*)p;         p += (size_t)NN * HID * 2;
    f16* h2 = (f16*)p;         p += (size_t)NN * HID * 2;
    f16* bt1 = (f16*)p;        p += 64 * 104 * 2;
    f16* bt2 = (f16*)p;        p += 64 * 136 * 2;
    f16* stab16 = (f16*)p;     p += 256 * 2;
    f16* ctab16 = (f16*)p;     p += 256 * 2;
    f16* ptab16 = (f16*)p;     p += 8192 * 2;
    float* stats = (float*)p;  p += 256 * 4;
    int* bcnt = (int*)p;       p += NBUK * 4;
    int* ids = (int*)p;        p += (size_t)NN * 4;
    int* row_ptr = (int*)p;    p += (NN + 1) * 4;
    int* gstart = (int*)p;     p += (NG + 1) * 4;
    int* bstart = (int*)p;     p += (NBUK + 1) * 4;
    int* bhistT = (int*)p;     p += (size_t)NBUK * NBBP * 4;
    int* lbaseT = (int*)p;     p += (size_t)NBUK * NBBP * 4;
    int* ebuf = (int*)p;       p += (size_t)NE * 4;
    int* eidx = (int*)p;       p += (size_t)NE * 4;

    const int B = 256;

    setup<<<721, B, 0, stream>>>(sid, cid, pid, batch, stab, ctab, ptab,
                                 W1l, W1r, W2l, W2r,
                                 ids, bt1, bt2, gstart, stab16, ctab16, ptab16,
                                 stats, bcnt);

    khist<<<NBB, B, 0, stream>>>(dst, bhistT, bcnt);
    kscan_a<<<1, 1024, 0, stream>>>(bcnt, bstart);
    kscan_b<<<NBUK, 64, 0, stream>>>(bhistT, bstart, lbaseT);
    kbin<<<NBB, B, 0, stream>>>(src, dst, lbaseT, ebuf);
    kfill<<<NBUK, B, 0, stream>>>(ebuf, bstart, row_ptr, eidx);

    // ---- layer 1 ----
    gather1<<<(NN * 64 + B - 1) / B, B, 0, stream>>>(row_ptr, eidx, ids,
                                                     stab16, ctab16, ptab16, agg);
    sage_mfma1<<<NN / 64, B, 0, stream>>>(ids, agg, stab16, ctab16, ptab16,
                                          bt1, b1, h1, stats);
    bn_apply16<<<(NN * 8 + B - 1) / B, B, 0, stream>>>(h1, stats, g1, be1);

    // ---- layer 2 (h1 now holds x1 = relu(bn1(h1))) ----
    gather2<<<(NN * 64 + B - 1) / B, B, 0, stream>>>(row_ptr, eidx, h1, agg);
    sage_mfma2<<<NN / 64, B, 0, stream>>>(h1, agg, bt2, b2, h2, stats + 128);

    // ---- fused BN2+ReLU+pool+head ----
    pool_out<<<(NG * 64 + B - 1) / B, B, 0, stream>>>(h2, stats + 128, g2, be2, gstart,
                                                      Wout, bout, (float*)d_out);
}

// Round 15
// 215.487 us; speedup vs baseline: 1.1623x; 1.0587x over previous
//
#include <hip/hip_runtime.h>

#define NN 80000
#define NE 1280000
#define NG 2000
#define HID 64
#define FIN1 40
#define BSZ 128
#define NBUK (NN / BSZ)                  // 625 buckets
#define EB 8192
#define NBB ((NE + EB - 1) / EB)         // 157 blocks
#define NBBP 160
constexpr float EPS = 1e-5f;

typedef _Float16 f16;
typedef f16 f16x8 __attribute__((ext_vector_type(8)));
typedef float f32x4 __attribute__((ext_vector_type(4)));

// ------- setup2: ids | wprep | graph bounds | f16 tables | zero stats | khist
__global__ void setup2(const int* __restrict__ sid, const int* __restrict__ cid,
                       const int* __restrict__ pid, const int* __restrict__ batch,
                       const float* __restrict__ stab, const float* __restrict__ ctab,
                       const float* __restrict__ ptab,
                       const float* __restrict__ W1l, const float* __restrict__ W1r,
                       const float* __restrict__ W2l, const float* __restrict__ W2r,
                       const int* __restrict__ dst,
                       int* __restrict__ ids, f16* __restrict__ Bt1, f16* __restrict__ Bt2,
                       int* __restrict__ gstart,
                       f16* __restrict__ stab16, f16* __restrict__ ctab16,
                       f16* __restrict__ ptab16,
                       float* __restrict__ stats,
                       int* __restrict__ bhistT, int* __restrict__ bcnt) {
    __shared__ int lh[NBUK];
    int bid = blockIdx.x;
    int tid = threadIdx.x;
    if (bid < 313) {                        // A: ids pack
        int n = bid * 256 + tid;
        if (n < NN) ids[n] = sid[n] | (cid[n] << 4) | (pid[n] << 8);
    } else if (bid < 373) {                 // B: wprep
        int i = (bid - 313) * 256 + tid;
        if (i < 64 * 104) {
            int j = i / 104, k = i - j * 104;
            float v = 0.f;
            if (k < 40) v = W1l[k * 64 + j];
            else if (k < 80) v = W1r[(k - 40) * 64 + j];
            Bt1[i] = (f16)v;
        }
        int i2 = i - 64 * 104;
        if (i2 >= 0 && i2 < 64 * 136) {
            int j = i2 / 136, k = i2 - j * 136;
            float v = 0.f;
            if (k < 64) v = W2l[k * 64 + j];
            else if (k < 128) v = W2r[(k - 64) * 64 + j];
            Bt2[i2] = (f16)v;
        }
    } else if (bid < 686) {                 // C: graph bounds
        int n = (bid - 373) * 256 + tid;
        if (n >= NN) return;
        int cur = batch[n];
        int prev = (n == 0) ? -1 : batch[n - 1];
        for (int g = prev + 1; g <= cur; g++) gstart[g] = n;
        if (n == NN - 1)
            for (int g = cur + 1; g <= NG; g++) gstart[g] = NN;
    } else if (bid < 720) {                 // D: f16 tables
        int i = (bid - 686) * 256 + tid;
        if (i < 256) stab16[i] = (f16)stab[i];
        else if (i < 512) ctab16[i - 256] = (f16)ctab[i - 256];
        else if (i < 512 + 8192) ptab16[i - 512] = (f16)ptab[i - 512];
    } else if (bid == 720) {                // E: zero stats (read after setup)
        if (tid < 256) stats[tid] = 0.f;
    } else {                                // F: khist (bcnt pre-zeroed by memset)
        int kb = bid - 721;
        for (int i = tid; i < NBUK; i += 256) lh[i] = 0;
        __syncthreads();
        int e0 = kb * EB, e1 = min(e0 + EB, NE);
        for (int e = e0 + tid; e < e1; e += 256) atomicAdd(&lh[dst[e] >> 7], 1);
        __syncthreads();
        for (int i = tid; i < NBUK; i += 256) {
            int c = lh[i];
            bhistT[i * NBBP + kb] = c;
            if (c) atomicAdd(&bcnt[i], c);
        }
    }
}

// ---------------- kscan: self-sufficient per-bucket scan ----------------
// block b (1 wave): bstart[b] = sum bcnt[0..b) ; lbaseT[b][blk] prefix
__global__ void kscan(const int* __restrict__ bcnt, const int* __restrict__ bhistT,
                      int* __restrict__ bstart, int* __restrict__ lbaseT) {
    int b = blockIdx.x;
    int l = threadIdx.x;               // 64 lanes
    int s = 0;
    for (int i = l; i < b; i += 64) s += bcnt[i];
#pragma unroll
    for (int off = 1; off < 64; off <<= 1) s += __shfl_xor(s, off);
    if (l == 0) bstart[b] = s;
    if (b == 0 && l == 0) bstart[NBUK] = NE;
    int run = s;
    for (int i0 = 0; i0 < NBB; i0 += 64) {
        int idx = i0 + l;
        int v = (idx < NBB) ? bhistT[b * NBBP + idx] : 0;
        int inc = v;
#pragma unroll
        for (int off = 1; off < 64; off <<= 1) {
            int tt = __shfl_up(inc, off);
            if (l >= off) inc += tt;
        }
        if (idx < NBB) lbaseT[b * NBBP + idx] = run + inc - v;
        run += __shfl(inc, 63);
    }
}

__global__ void kbin(const int* __restrict__ src, const int* __restrict__ dst,
                     const int* __restrict__ lbaseT, int* __restrict__ ebuf) {
    __shared__ int lcur[NBUK];
    for (int i = threadIdx.x; i < NBUK; i += 256) lcur[i] = lbaseT[i * NBBP + blockIdx.x];
    __syncthreads();
    int e0 = blockIdx.x * EB, e1 = min(e0 + EB, NE);
    for (int e = e0 + threadIdx.x; e < e1; e += 256) {
        int d = dst[e];
        int off = atomicAdd(&lcur[d >> 7], 1);
        ebuf[off] = (src[e] << 7) | (d & 127);
    }
}

__global__ void kfill(const int* __restrict__ ebuf, const int* __restrict__ bstart,
                      int* __restrict__ row_ptr, int* __restrict__ eidx) {
    __shared__ int cnt[BSZ];
    __shared__ int sb[BSZ];
    __shared__ int lcur[BSZ];
    int b = blockIdx.x, t = threadIdx.x;
    int nbase = b << 7;
    if (t < BSZ) cnt[t] = 0;
    __syncthreads();
    int s0 = bstart[b], s1 = bstart[b + 1];
    for (int i = s0 + t; i < s1; i += 256) atomicAdd(&cnt[ebuf[i] & 127], 1);
    __syncthreads();
    if (t < BSZ) sb[t] = cnt[t];
    __syncthreads();
    for (int off = 1; off < BSZ; off <<= 1) {
        int v = (t >= off && t < BSZ) ? sb[t - off] : 0;
        __syncthreads();
        if (t < BSZ) sb[t] += v;
        __syncthreads();
    }
    if (t < BSZ) {
        int excl = ((t == 0) ? 0 : sb[t - 1]) + s0;
        row_ptr[nbase + t] = excl;
        lcur[t] = excl;
    }
    if (b == 0 && t == 0) row_ptr[NN] = NE;
    __syncthreads();
    for (int i = s0 + t; i < s1; i += 256) {
        int v = ebuf[i];
        int pos = atomicAdd(&lcur[v & 127], 1);
        eidx[pos] = v >> 7;
    }
}

// ---------------- layer-1 gather: packed-f16 accumulate ----------------
__global__ void gather1(const int* __restrict__ row_ptr, const int* __restrict__ eidx,
                        const int* __restrict__ ids,
                        const f16* __restrict__ stab16, const f16* __restrict__ ctab16,
                        const f16* __restrict__ ptab16, f16* __restrict__ agg) {
    int tt = blockIdx.x * 256 + threadIdx.x;
    int n = tt >> 6;
    int lane = threadIdx.x & 63;
    if (n >= NN) return;
    int grp = lane >> 3, li = lane & 7;
    bool act = li < 5;
    int beg = row_ptr[n], end = row_ptr[n + 1];
    f16x8 ach;
#pragma unroll
    for (int i = 0; i < 8; i++) ach[i] = (f16)0.f;
    for (int j0 = beg; j0 < end; j0 += 64) {
        int cnt = min(64, end - j0);
        int myid = (j0 + lane < end) ? eidx[j0 + lane] : 0;
        int steps = (cnt + 7) >> 3;
        for (int u = 0; u < steps; u++) {
            int e = u * 8 + grp;
            int s = __shfl(myid, e);
            if (e < cnt && act) {
                int id = ids[s];
                const f16* rowp;
                if (li < 2)      rowp = &stab16[(id & 15) * 16 + li * 8];
                else if (li < 4) rowp = &ctab16[((id >> 4) & 15) * 16 + (li - 2) * 8];
                else             rowp = &ptab16[(id >> 8) * 8];
                ach += *(const f16x8*)rowp;
            }
        }
    }
    float ac[8];
#pragma unroll
    for (int i = 0; i < 8; i++) ac[i] = (float)ach[i];
#pragma unroll
    for (int m = 8; m <= 32; m <<= 1) {
#pragma unroll
        for (int i = 0; i < 8; i++) ac[i] += __shfl_xor(ac[i], m);
    }
    if (lane < 5) {
        float inv = 1.0f / (float)max(end - beg, 1);
        f16x8 o;
#pragma unroll
        for (int i = 0; i < 8; i++) o[i] = (f16)(ac[i] * inv);
        *(f16x8*)&agg[(size_t)n * FIN1 + lane * 8] = o;
    }
}

// ---------------- BN apply + ReLU, in-place f16 (h1 -> x1) ----------------
__global__ void bn_apply16(f16* __restrict__ h, const float* __restrict__ stats,
                           const float* __restrict__ g, const float* __restrict__ be) {
    __shared__ float ssc[64], ssh[64];
    int tid = threadIdx.x;
    if (tid < 64) {
        const float invn = 1.0f / (float)NN;
        float m = stats[tid] * invn;
        float var = stats[64 + tid] * invn - m * m;
        float sc = g[tid] * __frsqrt_rn(var + EPS);
        ssc[tid] = sc;
        ssh[tid] = be[tid] - m * sc;
    }
    __syncthreads();
    int idx = blockIdx.x * 256 + tid;
    if (idx >= NN * 8) return;
    int f = (idx & 7) * 8;
    f16x8 v = *(f16x8*)&h[(size_t)idx * 8];
    f16x8 o;
#pragma unroll
    for (int i = 0; i < 8; i++) {
        float xv = (float)v[i];
        o[i] = (f16)fmaxf(fmaf(xv, ssc[f + i], ssh[f + i]), 0.f);
    }
    *(f16x8*)&h[(size_t)idx * 8] = o;
}

// ---------------- layer-2 gather: raw sum, packed-f16 accumulate ------------
__global__ void gather2(const int* __restrict__ row_ptr, const int* __restrict__ eidx,
                        const f16* __restrict__ x, f16* __restrict__ agg) {
    int tt = blockIdx.x * 256 + threadIdx.x;
    int n = tt >> 6;
    int lane = threadIdx.x & 63;
    if (n >= NN) return;
    int grp = lane >> 3;
    int fl = (lane & 7) * 8;
    int beg = row_ptr[n], end = row_ptr[n + 1];
    f16x8 ach;
#pragma unroll
    for (int i = 0; i < 8; i++) ach[i] = (f16)0.f;
    for (int j0 = beg; j0 < end; j0 += 64) {
        int cnt = min(64, end - j0);
        int myid = (j0 + lane < end) ? eidx[j0 + lane] : 0;
        int steps = (cnt + 7) >> 3;
        for (int u = 0; u < steps; u++) {
            int e = u * 8 + grp;
            int s = __shfl(myid, e);
            if (e < cnt) {
                ach += *(const f16x8*)&x[(size_t)s * HID + fl];
            }
        }
    }
    float ac[8];
#pragma unroll
    for (int i = 0; i < 8; i++) ac[i] = (float)ach[i];
#pragma unroll
    for (int m = 8; m <= 32; m <<= 1) {
#pragma unroll
        for (int i = 0; i < 8; i++) ac[i] += __shfl_xor(ac[i], m);
    }
    if (lane < 8) {
        float inv = 1.0f / (float)max(end - beg, 1);
        f16x8 o;
#pragma unroll
        for (int i = 0; i < 8; i++) o[i] = (f16)(ac[i] * inv);
        *(f16x8*)&agg[(size_t)n * HID + fl] = o;
    }
}

// ---------------- MFMA layer 1: LDS-free fragments, fused BN stats ----------
__launch_bounds__(256)
__global__ void sage_mfma1(const int* __restrict__ ids, const f16* __restrict__ aggv,
                           const f16* __restrict__ stab16, const f16* __restrict__ ctab16,
                           const f16* __restrict__ ptab16,
                           const f16* __restrict__ Btg, const float* __restrict__ bias,
                           f16* __restrict__ h, float* __restrict__ stats) {
    __shared__ float sred[4][64];
    __shared__ float qred[4][64];
    const int KP = 104;

    int tid = threadIdx.x;
    int n0 = blockIdx.x * 64;
    int w = tid >> 6, l = tid & 63;
    int jloc = l & 15, kg = l >> 4;
    int n = n0 + w * 16 + jloc;

    f16x8 af[3];
#pragma unroll
    for (int kk = 0; kk < 3; kk++) {
        int c = kk * 4 + kg;
        if (c < 5) {
            af[kk] = *(const f16x8*)&aggv[(size_t)n * FIN1 + c * 8];
        } else if (c < 10) {
            int id = ids[n];
            int cc = c - 5;
            const f16* rowp;
            if (cc < 2)      rowp = &stab16[(id & 15) * 16 + cc * 8];
            else if (cc < 4) rowp = &ctab16[((id >> 4) & 15) * 16 + (cc - 2) * 8];
            else             rowp = &ptab16[(id >> 8) * 8];
            af[kk] = *(const f16x8*)rowp;
        } else {
#pragma unroll
            for (int i = 0; i < 8; i++) af[kk][i] = (f16)0.f;
        }
    }

    f32x4 acc[4];
#pragma unroll
    for (int jt = 0; jt < 4; jt++) {
        float bj = bias[jt * 16 + jloc];
        acc[jt] = (f32x4){bj, bj, bj, bj};
    }
#pragma unroll
    for (int kk = 0; kk < 3; kk++) {
#pragma unroll
        for (int jt = 0; jt < 4; jt++) {
            f16x8 bf = *(const f16x8*)&Btg[(jt * 16 + jloc) * KP + kk * 32 + kg * 8];
            acc[jt] = __builtin_amdgcn_mfma_f32_16x16x32_f16(af[kk], bf, acc[jt], 0, 0, 0);
        }
    }
#pragma unroll
    for (int jt = 0; jt < 4; jt++) {
        float sv = 0.f, qv = 0.f;
#pragma unroll
        for (int reg = 0; reg < 4; reg++) {
            f16 hv = (f16)acc[jt][reg];
            int nn2 = n0 + w * 16 + kg * 4 + reg;
            h[(size_t)nn2 * HID + jt * 16 + jloc] = hv;
            float v = (float)hv;
            sv += v; qv += v * v;
        }
        sv += __shfl_xor(sv, 16); sv += __shfl_xor(sv, 32);
        qv += __shfl_xor(qv, 16); qv += __shfl_xor(qv, 32);
        if (kg == 0) { sred[w][jt * 16 + jloc] = sv; qred[w][jt * 16 + jloc] = qv; }
    }
    __syncthreads();
    if (tid < 128) {
        int f2 = tid & 63, which = tid >> 6;
        float r = which ? (qred[0][f2] + qred[1][f2] + qred[2][f2] + qred[3][f2])
                        : (sred[0][f2] + sred[1][f2] + sred[2][f2] + sred[3][f2]);
        atomicAdd(&stats[which * 64 + f2], r);
    }
}

// ---------------- MFMA layer 2: LDS-free fragments, fused BN2 stats ---------
__launch_bounds__(256)
__global__ void sage_mfma2(const f16* __restrict__ x, const f16* __restrict__ aggv,
                           const f16* __restrict__ Btg, const float* __restrict__ bias,
                           f16* __restrict__ h, float* __restrict__ stats) {
    __shared__ float sred[4][64];
    __shared__ float qred[4][64];
    const int KP = 136;

    int tid = threadIdx.x;
    int n0 = blockIdx.x * 64;
    int w = tid >> 6, l = tid & 63;
    int jloc = l & 15, kg = l >> 4;
    int n = n0 + w * 16 + jloc;

    f16x8 af[4];
#pragma unroll
    for (int kk = 0; kk < 4; kk++) {
        int c = kk * 4 + kg;
        if (c < 8) af[kk] = *(const f16x8*)&aggv[(size_t)n * HID + c * 8];
        else       af[kk] = *(const f16x8*)&x[(size_t)n * HID + (c - 8) * 8];
    }

    f32x4 acc[4];
#pragma unroll
    for (int jt = 0; jt < 4; jt++) {
        float bj = bias[jt * 16 + jloc];
        acc[jt] = (f32x4){bj, bj, bj, bj};
    }
#pragma unroll
    for (int kk = 0; kk < 4; kk++) {
#pragma unroll
        for (int jt = 0; jt < 4; jt++) {
            f16x8 bf = *(const f16x8*)&Btg[(jt * 16 + jloc) * KP + kk * 32 + kg * 8];
            acc[jt] = __builtin_amdgcn_mfma_f32_16x16x32_f16(af[kk], bf, acc[jt], 0, 0, 0);
        }
    }
#pragma unroll
    for (int jt = 0; jt < 4; jt++) {
        float sv = 0.f, qv = 0.f;
#pragma unroll
        for (int reg = 0; reg < 4; reg++) {
            f16 hv = (f16)acc[jt][reg];
            int nn2 = n0 + w * 16 + kg * 4 + reg;
            h[(size_t)nn2 * HID + jt * 16 + jloc] = hv;
            float v = (float)hv;
            sv += v; qv += v * v;
        }
        sv += __shfl_xor(sv, 16); sv += __shfl_xor(sv, 32);
        qv += __shfl_xor(qv, 16); qv += __shfl_xor(qv, 32);
        if (kg == 0) { sred[w][jt * 16 + jloc] = sv; qred[w][jt * 16 + jloc] = qv; }
    }
    __syncthreads();
    if (tid < 128) {
        int f2 = tid & 63, which = tid >> 6;
        float r = which ? (qred[0][f2] + qred[1][f2] + qred[2][f2] + qred[3][f2])
                        : (sred[0][f2] + sred[1][f2] + sred[2][f2] + sred[3][f2]);
        atomicAdd(&stats[which * 64 + f2], r);
    }
}

// ---------------- pool_out: block per graph, 4-wave segment split -----------
__global__ void pool_out(const f16* __restrict__ h, const float* __restrict__ stats2,
                         const float* __restrict__ g2, const float* __restrict__ be2,
                         const int* __restrict__ gstart,
                         const float* __restrict__ Wout, const float* __restrict__ bout,
                         float* __restrict__ out) {
    __shared__ float red[4][64];
    int w = blockIdx.x;
    int tid = threadIdx.x;
    int f = tid & 63, seg = tid >> 6;
    const float invn = 1.0f / (float)NN;
    float m = stats2[f] * invn;
    float var = stats2[64 + f] * invn - m * m;
    float sc = g2[f] / sqrtf(var + EPS);
    float sh = be2[f] - m * sc;
    int n0 = gstart[w], n1 = gstart[w + 1];
    float acc = 0.f;
    for (int n = n0 + seg; n < n1; n += 4) {
        float v = fmaf((float)h[(size_t)n * HID + f], sc, sh);
        acc += fmaxf(v, 0.0f);
    }
    red[seg][f] = acc;
    __syncthreads();
    if (seg == 0) {
        acc = red[0][f] + red[1][f] + red[2][f] + red[3][f];
        float inv = 1.0f / (float)max(n1 - n0, 1);
        float p = acc * inv;
        float a0 = p * Wout[f * 2 + 0];
        float a1 = p * Wout[f * 2 + 1];
#pragma unroll
        for (int mm = 1; mm < 64; mm <<= 1) {
            a0 += __shfl_xor(a0, mm);
            a1 += __shfl_xor(a1, mm);
        }
        if (f == 0) {
            out[w * 2 + 0] = a0 + bout[0];
            out[w * 2 + 1] = a1 + bout[1];
        }
    }
}

extern "C" void kernel_launch(void* const* d_in, const int* in_sizes, int n_in,
                              void* d_out, int out_size, void* d_ws, size_t ws_size,
                              hipStream_t stream) {
    const int* sid = (const int*)d_in[0];
    const int* cid = (const int*)d_in[1];
    const int* pid = (const int*)d_in[2];
    const int* ei = (const int*)d_in[3];
    const int* batch = (const int*)d_in[4];
    const float* stab = (const float*)d_in[6];
    const float* ctab = (const float*)d_in[7];
    const float* ptab = (const float*)d_in[8];
    const float* W1l = (const float*)d_in[9];
    const float* b1 = (const float*)d_in[10];
    const float* W1r = (const float*)d_in[11];
    const float* g1 = (const float*)d_in[12];
    const float* be1 = (const float*)d_in[13];
    const float* W2l = (const float*)d_in[14];
    const float* b2 = (const float*)d_in[15];
    const float* W2r = (const float*)d_in[16];
    const float* g2 = (const float*)d_in[17];
    const float* be2 = (const float*)d_in[18];
    const float* Wout = (const float*)d_in[19];
    const float* bout = (const float*)d_in[20];

    const int* src = ei;
    const int* dst = ei + NE;

    char* p = (char*)d_ws;
    f16* agg = (f16*)p;        p += (size_t)NN * HID * 2;
    f16* h1 = (f16*)p;         p += (size_t)NN * HID * 2;
    f16* h2 = (f16*)p;         p += (size_t)NN * HID * 2;
    f16* bt1 = (f16*)p;        p += 64 * 104 * 2;
    f16* bt2 = (f16*)p;        p += 64 * 136 * 2;
    f16* stab16 = (f16*)p;     p += 256 * 2;
    f16* ctab16 = (f16*)p;     p += 256 * 2;
    f16* ptab16 = (f16*)p;     p += 8192 * 2;
    float* stats = (float*)p;  p += 256 * 4;
    int* bcnt = (int*)p;       p += NBUK * 4;
    int* ids = (int*)p;        p += (size_t)NN * 4;
    int* row_ptr = (int*)p;    p += (NN + 1) * 4;
    int* gstart = (int*)p;     p += (NG + 1) * 4;
    int* bstart = (int*)p;     p += (NBUK + 1) * 4;
    int* bhistT = (int*)p;     p += (size_t)NBUK * NBBP * 4;
    int* lbaseT = (int*)p;     p += (size_t)NBUK * NBBP * 4;
    int* ebuf = (int*)p;       p += (size_t)NE * 4;
    int* eidx = (int*)p;       p += (size_t)NE * 4;

    const int B = 256;

    // bcnt must be zero BEFORE setup2 (khist region atomics run inside it)
    hipMemsetAsync(bcnt, 0, NBUK * sizeof(int), stream);

    setup2<<<721 + NBB, B, 0, stream>>>(sid, cid, pid, batch, stab, ctab, ptab,
                                        W1l, W1r, W2l, W2r, dst,
                                        ids, bt1, bt2, gstart, stab16, ctab16, ptab16,
                                        stats, bhistT, bcnt);

    kscan<<<NBUK, 64, 0, stream>>>(bcnt, bhistT, bstart, lbaseT);
    kbin<<<NBB, B, 0, stream>>>(src, dst, lbaseT, ebuf);
    kfill<<<NBUK, B, 0, stream>>>(ebuf, bstart, row_ptr, eidx);

    // ---- layer 1 ----
    gather1<<<(NN * 64 + B - 1) / B, B, 0, stream>>>(row_ptr, eidx, ids,
                                                     stab16, ctab16, ptab16, agg);
    sage_mfma1<<<NN / 64, B, 0, stream>>>(ids, agg, stab16, ctab16, ptab16,
                                          bt1, b1, h1, stats);
    bn_apply16<<<(NN * 8 + B - 1) / B, B, 0, stream>>>(h1, stats, g1, be1);

    // ---- layer 2 (h1 now holds x1 = relu(bn1(h1))) ----
    gather2<<<(NN * 64 + B - 1) / B, B, 0, stream>>>(row_ptr, eidx, h1, agg);
    sage_mfma2<<<NN / 64, B, 0, stream>>>(h1, agg, bt2, b2, h2, stats + 128);

    // ---- fused BN2+ReLU+pool+head ----
    pool_out<<<NG, B, 0, stream>>>(h2, stats + 128, g2, be2, gstart,
                                   Wout, bout, (float*)d_out);
}